// Round 1
// baseline (31365.594 us; speedup 1.0000x reference)
//
#include <hip/hip_runtime.h>
#include <hip/hip_bf16.h>
#include <math.h>

#define B_ 64
#define T_ 32
#define S_ 64
#define V_ 32000
#define E_ 512
#define H_ 1024
#define C_ 2048
#define G_ (3*H_)

// ---------------- GEMM: out[m,n] (+)= sum_k A[m*lda+k] * W(k,n) ----------------
// TRANSB: W is [N,K] row-major (use W[n*K+k])  -> A @ W^T
// !TRANSB: W is [K,N] row-major (use W[k*N+n]) -> A @ W
#define BM 64
#define BN 64
#define BK 32

template<bool TRANSB, bool ACCUM>
__global__ __launch_bounds__(256)
void gemm_kernel(const float* __restrict__ A, int lda,
                 const float* __restrict__ W,
                 float* __restrict__ out,
                 int M, int N, int K)
{
    __shared__ float As[BK][BM + 4];
    __shared__ float Bs[BK][BN + 4];
    const int tid = threadIdx.x;
    const int tx = tid & 15, ty = tid >> 4;
    const int n0 = blockIdx.x * BN;
    const int m0 = blockIdx.y * BM;

    float acc[4][4] = {};

    for (int k0 = 0; k0 < K; k0 += BK) {
        // load A tile (BM x BK)
        for (int e = tid; e < BM * BK; e += 256) {
            int m = e >> 5, kk = e & 31;
            As[kk][m] = A[(size_t)(m0 + m) * lda + k0 + kk];
        }
        if (TRANSB) {
            for (int e = tid; e < BN * BK; e += 256) {
                int n = e >> 5, kk = e & 31;
                Bs[kk][n] = W[(size_t)(n0 + n) * K + k0 + kk];
            }
        } else {
            for (int e = tid; e < BN * BK; e += 256) {
                int kk = e >> 6, n = e & 63;
                Bs[kk][n] = W[(size_t)(k0 + kk) * N + n0 + n];
            }
        }
        __syncthreads();
        #pragma unroll
        for (int kk = 0; kk < BK; ++kk) {
            float a[4], b[4];
            #pragma unroll
            for (int i = 0; i < 4; ++i) a[i] = As[kk][ty * 4 + i];
            #pragma unroll
            for (int j = 0; j < 4; ++j) b[j] = Bs[kk][tx * 4 + j];
            #pragma unroll
            for (int i = 0; i < 4; ++i)
                #pragma unroll
                for (int j = 0; j < 4; ++j)
                    acc[i][j] += a[i] * b[j];
        }
        __syncthreads();
    }
    #pragma unroll
    for (int i = 0; i < 4; ++i) {
        int m = m0 + ty * 4 + i;
        #pragma unroll
        for (int j = 0; j < 4; ++j) {
            int n = n0 + tx * 4 + j;
            if (ACCUM) out[(size_t)m * N + n] += acc[i][j];
            else       out[(size_t)m * N + n]  = acc[i][j];
        }
    }
}

// ---------------- embedding lookup ----------------
__global__ __launch_bounds__(256)
void embed_kernel(const int* __restrict__ y, const float* __restrict__ emb,
                  float* __restrict__ x)
{
    int i = blockIdx.x * 256 + threadIdx.x;      // over B*T*E/4
    int row = i / (E_ / 4);
    int e4  = i % (E_ / 4);
    const float4* src = (const float4*)(emb + (size_t)y[row] * E_);
    ((float4*)(x + (size_t)row * E_))[e4] = src[e4];
}

// ---------------- GRU combine ----------------
__global__ __launch_bounds__(256)
void gru_kernel(const float* __restrict__ gi, int gi_stride,
                const float* __restrict__ gh,
                const float* __restrict__ b_ih, const float* __restrict__ b_hh,
                const float* __restrict__ h_prev,
                float* __restrict__ h_out,
                float* __restrict__ h_out2, int h2_stride)
{
    int idx = blockIdx.x * 256 + threadIdx.x;     // B*H
    int b = idx >> 10, j = idx & (H_ - 1);
    const float* gir = gi + (size_t)b * gi_stride;
    const float* ghr = gh + (size_t)b * G_;
    float ir = gir[j]          + b_ih[j];
    float iz = gir[H_ + j]     + b_ih[H_ + j];
    float in_ = gir[2*H_ + j]  + b_ih[2*H_ + j];
    float hr = ghr[j]          + b_hh[j];
    float hz = ghr[H_ + j]     + b_hh[H_ + j];
    float hn = ghr[2*H_ + j]   + b_hh[2*H_ + j];
    float r = 1.f / (1.f + expf(-(ir + hr)));
    float z = 1.f / (1.f + expf(-(iz + hz)));
    float n = tanhf(in_ + r * hn);
    float h = (1.f - z) * n + z * h_prev[idx];
    h_out[idx] = h;
    if (h_out2) h_out2[(size_t)b * h2_stride + j] = h;
}

// ---------------- attention (one block per batch element) ----------------
__global__ __launch_bounds__(1024)
void attn_kernel(const float* __restrict__ qraw,     // [B,H] (no bias)
                 const float* __restrict__ bq,       // [H]
                 const float* __restrict__ cacheK,   // [B,S,H]
                 const float* __restrict__ v_attn,   // [H]
                 const int*   __restrict__ mask,     // [B,S]
                 const float* __restrict__ context,  // [B,S,C]
                 float* __restrict__ attn_out)       // ptr at +t*C, row stride T*C
{
    const int b = blockIdx.x;
    const int tid = threadIdx.x;
    const int lane = tid & 63, wave = tid >> 6;      // 16 waves

    __shared__ float qb[H_];
    __shared__ float vs[H_];
    __shared__ float sc[S_];
    __shared__ float pr[S_];

    for (int h = tid; h < H_; h += 1024) {
        qb[h] = qraw[(size_t)b * H_ + h] + bq[h];
        vs[h] = v_attn[h];
    }
    __syncthreads();

    // scores[s] = sum_h tanh(qb[h] + cache[b,s,h]) * v[h]
    for (int s = wave; s < S_; s += 16) {
        const float* cr = cacheK + ((size_t)b * S_ + s) * H_;
        float sum = 0.f;
        for (int h = lane; h < H_; h += 64)
            sum += tanhf(qb[h] + cr[h]) * vs[h];
        #pragma unroll
        for (int off = 32; off; off >>= 1) sum += __shfl_down(sum, off, 64);
        if (lane == 0) sc[s] = sum;
    }
    __syncthreads();

    // softmax over S (wave 0 handles it; S == 64 lanes)
    if (wave == 0) {
        float v = (mask[b * S_ + lane] != 0) ? -3.4e38f : sc[lane];
        float mx = v;
        #pragma unroll
        for (int off = 32; off; off >>= 1) mx = fmaxf(mx, __shfl_xor(mx, off, 64));
        float e = expf(v - mx);
        float sum = e;
        #pragma unroll
        for (int off = 32; off; off >>= 1) sum += __shfl_xor(sum, off, 64);
        pr[lane] = e / sum;
    }
    __syncthreads();

    // attn[c] = sum_s pr[s] * context[b,s,c]
    for (int c = tid; c < C_; c += 1024) {
        const float* cb = context + (size_t)b * S_ * C_ + c;
        float sum = 0.f;
        #pragma unroll 8
        for (int s = 0; s < S_; ++s)
            sum += pr[s] * cb[(size_t)s * C_];
        attn_out[(size_t)b * (T_ * C_) + c] = sum;
    }
}

// ---------------- final logits + h_final ----------------
__global__ __launch_bounds__(256)
void final_kernel(const float* __restrict__ L,
                  const float* __restrict__ bi, const float* __restrict__ bh,
                  const float* __restrict__ bc,
                  const float* __restrict__ h_cur,
                  float* __restrict__ out)
{
    int i = blockIdx.x * 256 + threadIdx.x;
    const int total = B_ * T_ * E_;
    if (i < total) {
        int e = i & (E_ - 1);
        out[i] = tanhf(L[i] + bi[e] + bh[e] + bc[e]);
    } else if (i < total + B_ * H_) {
        out[i] = h_cur[i - total];
    }
}

extern "C" void kernel_launch(void* const* d_in, const int* in_sizes, int n_in,
                              void* d_out, int out_size, void* d_ws, size_t ws_size,
                              hipStream_t stream)
{
    const int*   y       = (const int*)  d_in[0];
    const float* context = (const float*)d_in[1];
    const int*   cmask   = (const int*)  d_in[2];
    const float* hidden  = (const float*)d_in[3];
    const float* emb     = (const float*)d_in[4];
    const float* W_ih1   = (const float*)d_in[5];
    const float* W_hh1   = (const float*)d_in[6];
    const float* b_ih1   = (const float*)d_in[7];
    const float* b_hh1   = (const float*)d_in[8];
    const float* Wq      = (const float*)d_in[9];
    const float* bq      = (const float*)d_in[10];
    const float* Wk      = (const float*)d_in[11];
    const float* v_attn  = (const float*)d_in[12];
    const float* W_ih2   = (const float*)d_in[13];
    const float* W_hh2   = (const float*)d_in[14];
    const float* b_ih2   = (const float*)d_in[15];
    const float* b_hh2   = (const float*)d_in[16];
    const float* Wi      = (const float*)d_in[17];
    const float* bi      = (const float*)d_in[18];
    const float* Wh      = (const float*)d_in[19];
    const float* bh      = (const float*)d_in[20];
    const float* Wc      = (const float*)d_in[21];
    const float* bc      = (const float*)d_in[22];

    float* ws = (float*)d_ws;
    size_t off = 0;
    float* x        = ws + off; off += (size_t)B_ * T_ * E_;   // 1,048,576
    float* Xg       = ws + off; off += (size_t)B_ * T_ * G_;   // 6,291,456
    float* Xi       = ws + off; off += (size_t)B_ * T_ * E_;   // 1,048,576
    float* cacheK   = ws + off; off += (size_t)B_ * S_ * H_;   // 4,194,304
    float* attn_seq = ws + off; off += (size_t)B_ * T_ * C_;   // 4,194,304
    float* out_seq  = ws + off; off += (size_t)B_ * T_ * H_;   // 2,097,152
    float* gh1      = ws + off; off += (size_t)B_ * G_;
    float* gi2      = ws + off; off += (size_t)B_ * G_;
    float* gh2      = ws + off; off += (size_t)B_ * G_;
    float* qbuf     = ws + off; off += (size_t)B_ * H_;
    float* h1       = ws + off; off += (size_t)B_ * H_;
    float* h_cur    = ws + off; off += (size_t)B_ * H_;

    // ---- hoisted precomputes ----
    embed_kernel<<<(B_*T_*E_/4 + 255)/256, 256, 0, stream>>>(y, emb, x);

    // Xg = x @ W_ih1^T   [2048, 3072], K=512
    gemm_kernel<true, false><<<dim3(G_/BN, (B_*T_)/BM), 256, 0, stream>>>(
        x, E_, W_ih1, Xg, B_*T_, G_, E_);
    // Xi = x @ Wi^T      [2048, 512], K=512
    gemm_kernel<true, false><<<dim3(E_/BN, (B_*T_)/BM), 256, 0, stream>>>(
        x, E_, Wi, Xi, B_*T_, E_, E_);
    // cacheK = context @ Wk   [4096, 1024], K=2048
    gemm_kernel<false, false><<<dim3(H_/BN, (B_*S_)/BM), 256, 0, stream>>>(
        context, C_, Wk, cacheK, B_*S_, H_, C_);

    // ---- sequential scan ----
    for (int t = 0; t < T_; ++t) {
        const float* hprev = (t == 0) ? hidden : h_cur;

        // gh1 = hprev @ W_hh1^T   [64, 3072], K=1024
        gemm_kernel<true, false><<<dim3(G_/BN, 1), 256, 0, stream>>>(
            hprev, H_, W_hh1, gh1, B_, G_, H_);

        // h1 = gru(Xg_t, gh1, hprev)
        gru_kernel<<<(B_*H_)/256, 256, 0, stream>>>(
            Xg + (size_t)t * G_, T_ * G_, gh1, b_ih1, b_hh1, hprev, h1,
            (float*)nullptr, 0);

        // q = h1 @ Wq   [64, 1024], K=1024 (bias added in attn kernel)
        gemm_kernel<false, false><<<dim3(H_/BN, 1), 256, 0, stream>>>(
            h1, H_, Wq, qbuf, B_, H_, H_);

        // attention -> attn_seq[:, t, :]
        attn_kernel<<<B_, 1024, 0, stream>>>(
            qbuf, bq, cacheK, v_attn, cmask, context, attn_seq + (size_t)t * C_);

        // gi2 = attn_t @ W_ih2^T   [64, 3072], K=2048
        gemm_kernel<true, false><<<dim3(G_/BN, 1), 256, 0, stream>>>(
            attn_seq + (size_t)t * C_, T_ * C_, W_ih2, gi2, B_, G_, C_);

        // gh2 = h1 @ W_hh2^T   [64, 3072], K=1024
        gemm_kernel<true, false><<<dim3(G_/BN, 1), 256, 0, stream>>>(
            h1, H_, W_hh2, gh2, B_, G_, H_);

        // h2 = gru(gi2, gh2, h1) -> h_cur and out_seq[:, t, :]
        gru_kernel<<<(B_*H_)/256, 256, 0, stream>>>(
            gi2, G_, gh2, b_ih2, b_hh2, h1, h_cur,
            out_seq + (size_t)t * H_, T_ * H_);
    }

    // ---- epilogue: L = Xi + out_seq @ Wh^T + attn_seq @ Wc^T ----
    gemm_kernel<true, true><<<dim3(E_/BN, (B_*T_)/BM), 256, 0, stream>>>(
        out_seq, H_, Wh, Xi, B_*T_, E_, H_);
    gemm_kernel<true, true><<<dim3(E_/BN, (B_*T_)/BM), 256, 0, stream>>>(
        attn_seq, C_, Wc, Xi, B_*T_, E_, C_);

    const int total_out = B_*T_*E_ + B_*H_;
    final_kernel<<<(total_out + 255)/256, 256, 0, stream>>>(
        Xi, bi, bh, bc, h_cur, (float*)d_out);
}

// Round 2
// 3954.235 us; speedup vs baseline: 7.9322x; 7.9322x over previous
//
#include <hip/hip_runtime.h>
#include <math.h>

#define B_ 64
#define T_ 32
#define S_ 64
#define V_ 32000
#define E_ 512
#define H_ 1024
#define C_ 2048
#define G_ (3*H_)
#define SPLITK 4

// ================= split-K skinny GEMM: A[64,K] @ W^T, W is [N,K] ==========
// Writes partials P[s][m*N+n], s = blockIdx.y over SPLITK K-chunks.
__global__ __launch_bounds__(256)
void splitk_gemm(const float* __restrict__ A, int lda,
                 const float* __restrict__ W,
                 float* __restrict__ P,
                 int N, int K)
{
    __shared__ float As[32][68];
    __shared__ float Bs[32][68];
    const int tid = threadIdx.x;
    const int n0 = blockIdx.x * 64;
    const int s  = blockIdx.y;
    const int Kc = K / SPLITK;
    const int kbeg = s * Kc;
    const int tx = tid & 15, ty = tid >> 4;

    float acc[4][4] = {};

    for (int k0 = kbeg; k0 < kbeg + Kc; k0 += 32) {
        #pragma unroll
        for (int p = 0; p < 2; ++p) {
            int e = tid + p * 256;            // 512 float4 = 64m x 32k
            int m = e >> 3, k4 = (e & 7) * 4;
            float4 v = *(const float4*)&A[(size_t)m * lda + k0 + k4];
            As[k4+0][m] = v.x; As[k4+1][m] = v.y;
            As[k4+2][m] = v.z; As[k4+3][m] = v.w;
        }
        #pragma unroll
        for (int p = 0; p < 2; ++p) {
            int e = tid + p * 256;            // 64n x 32k
            int n = e >> 3, k4 = (e & 7) * 4;
            float4 v = *(const float4*)&W[(size_t)(n0+n) * K + kbeg + (k0-kbeg) + k4];
            Bs[k4+0][n] = v.x; Bs[k4+1][n] = v.y;
            Bs[k4+2][n] = v.z; Bs[k4+3][n] = v.w;
        }
        __syncthreads();
        #pragma unroll
        for (int kk = 0; kk < 32; ++kk) {
            float4 av = *(const float4*)&As[kk][ty*4];
            float4 bv = *(const float4*)&Bs[kk][tx*4];
            float a[4] = {av.x, av.y, av.z, av.w};
            float b[4] = {bv.x, bv.y, bv.z, bv.w};
            #pragma unroll
            for (int i = 0; i < 4; ++i)
                #pragma unroll
                for (int j = 0; j < 4; ++j)
                    acc[i][j] += a[i] * b[j];
        }
        __syncthreads();
    }

    float* outp = P + (size_t)s * ((size_t)B_ * N);
    #pragma unroll
    for (int i = 0; i < 4; ++i) {
        size_t row = (size_t)(ty*4 + i) * N + n0;
        #pragma unroll
        for (int j = 0; j < 4; ++j)
            outp[row + tx*4 + j] = acc[i][j];
    }
}

// ================= 128x128-tile GEMM (8x8/thread) for big shapes ===========
template<bool TRANSB, bool ACCUM>
__global__ __launch_bounds__(256)
void gemm128(const float* __restrict__ A, int lda,
             const float* __restrict__ W,
             float* __restrict__ out,
             int M, int N, int K)
{
    __shared__ float As[16][132];
    __shared__ float Bs[16][132];
    const int tid = threadIdx.x;
    const int n0 = blockIdx.x * 128, m0 = blockIdx.y * 128;
    const int tx = tid & 15, ty = tid >> 4;

    float acc[8][8] = {};

    for (int k0 = 0; k0 < K; k0 += 16) {
        #pragma unroll
        for (int p = 0; p < 2; ++p) {
            int e = tid + p * 256;            // 512 float4 = 128m x 16k
            int m = e >> 2, k4 = (e & 3) * 4;
            float4 v = *(const float4*)&A[(size_t)(m0+m) * lda + k0 + k4];
            As[k4+0][m] = v.x; As[k4+1][m] = v.y;
            As[k4+2][m] = v.z; As[k4+3][m] = v.w;
        }
        if (TRANSB) {
            #pragma unroll
            for (int p = 0; p < 2; ++p) {
                int e = tid + p * 256;        // 128n x 16k
                int n = e >> 2, k4 = (e & 3) * 4;
                float4 v = *(const float4*)&W[(size_t)(n0+n) * K + k0 + k4];
                Bs[k4+0][n] = v.x; Bs[k4+1][n] = v.y;
                Bs[k4+2][n] = v.z; Bs[k4+3][n] = v.w;
            }
        } else {
            #pragma unroll
            for (int p = 0; p < 2; ++p) {
                int e = tid + p * 256;        // 16k x 128n
                int k = e >> 5, n4 = (e & 31) * 4;
                float4 v = *(const float4*)&W[(size_t)(k0+k) * N + n0 + n4];
                *(float4*)&Bs[k][n4] = v;
            }
        }
        __syncthreads();
        #pragma unroll
        for (int kk = 0; kk < 16; ++kk) {
            float a[8], b[8];
            *(float4*)&a[0] = *(const float4*)&As[kk][ty*8];
            *(float4*)&a[4] = *(const float4*)&As[kk][ty*8+4];
            *(float4*)&b[0] = *(const float4*)&Bs[kk][tx*8];
            *(float4*)&b[4] = *(const float4*)&Bs[kk][tx*8+4];
            #pragma unroll
            for (int i = 0; i < 8; ++i)
                #pragma unroll
                for (int j = 0; j < 8; ++j)
                    acc[i][j] += a[i] * b[j];
        }
        __syncthreads();
    }

    #pragma unroll
    for (int i = 0; i < 8; ++i) {
        size_t row = (size_t)(m0 + ty*8 + i) * N + n0 + tx*8;
        #pragma unroll
        for (int jv = 0; jv < 2; ++jv) {
            float4 v = {acc[i][jv*4+0], acc[i][jv*4+1], acc[i][jv*4+2], acc[i][jv*4+3]};
            if (ACCUM) {
                float4 o = *(float4*)&out[row + jv*4];
                v.x += o.x; v.y += o.y; v.z += o.z; v.w += o.w;
            }
            *(float4*)&out[row + jv*4] = v;
        }
    }
}

// ================= helpers =================
__global__ __launch_bounds__(256)
void embed_kernel(const int* __restrict__ y, const float* __restrict__ emb,
                  float* __restrict__ x)
{
    int i = blockIdx.x * 256 + threadIdx.x;      // B*T*E/4
    int row = i / (E_ / 4);
    int e4  = i % (E_ / 4);
    const float4* src = (const float4*)(emb + (size_t)y[row] * E_);
    ((float4*)(x + (size_t)row * E_))[e4] = src[e4];
}

__global__ void transpose_kernel(const float* __restrict__ in, float* __restrict__ out,
                                 int R, int Ccols)   // out[c][r] = in[r][c]
{
    __shared__ float t[32][33];
    int r0 = blockIdx.y * 32, c0 = blockIdx.x * 32;
    t[threadIdx.y][threadIdx.x] = in[(size_t)(r0 + threadIdx.y) * Ccols + c0 + threadIdx.x];
    __syncthreads();
    out[(size_t)(c0 + threadIdx.y) * R + r0 + threadIdx.x] = t[threadIdx.x][threadIdx.y];
}

__global__ __launch_bounds__(256)
void copy4_kernel(const float* __restrict__ in, float* __restrict__ out)
{
    int i = blockIdx.x * 256 + threadIdx.x;
    ((float4*)out)[i] = ((const float4*)in)[i];
}

// ================= GRU combines (sum split-K partials inline) ==============
__global__ __launch_bounds__(256)
void gru1_kernel(const float* __restrict__ Xg_t,        // + t*G, stride T*G
                 const float* __restrict__ P,           // [4][B*3072] gh1 partials
                 const float* __restrict__ b_ih, const float* __restrict__ b_hh,
                 const float* __restrict__ h_prev,
                 float* __restrict__ h_out)
{
    int idx = blockIdx.x * 256 + threadIdx.x;
    int b = idx >> 10, j = idx & (H_ - 1);
    const float* gi = Xg_t + (size_t)b * (T_ * G_);
    float hr = 0.f, hz = 0.f, hn = 0.f;
    #pragma unroll
    for (int s = 0; s < SPLITK; ++s) {
        const float* p = P + (size_t)s * (B_ * G_) + (size_t)b * G_;
        hr += p[j]; hz += p[H_ + j]; hn += p[2*H_ + j];
    }
    float ir = gi[j]         + b_ih[j]        + b_hh[j]        + hr;
    float iz = gi[H_ + j]    + b_ih[H_ + j]   + b_hh[H_ + j]   + hz;
    float in_ = gi[2*H_ + j] + b_ih[2*H_ + j];
    hn += b_hh[2*H_ + j];
    float r = 1.f / (1.f + expf(-ir));
    float z = 1.f / (1.f + expf(-iz));
    float n = tanhf(in_ + r * hn);
    h_out[idx] = (1.f - z) * n + z * h_prev[idx];
}

__global__ __launch_bounds__(256)
void gru2_kernel(const float* __restrict__ Pgi,   // [4][B*3072] gi2 partials
                 const float* __restrict__ Pqg,   // [4][B*4096], gh2 at +1024
                 const float* __restrict__ b_ih, const float* __restrict__ b_hh,
                 const float* __restrict__ h_prev,
                 float* __restrict__ h_out,
                 float* __restrict__ out_seq_t)   // + t*H, stride T*H
{
    int idx = blockIdx.x * 256 + threadIdx.x;
    int b = idx >> 10, j = idx & (H_ - 1);
    float ir = 0.f, iz = 0.f, in_ = 0.f, hr = 0.f, hz = 0.f, hn = 0.f;
    #pragma unroll
    for (int s = 0; s < SPLITK; ++s) {
        const float* pi = Pgi + (size_t)s * (B_ * G_) + (size_t)b * G_;
        ir += pi[j]; iz += pi[H_ + j]; in_ += pi[2*H_ + j];
        const float* ph = Pqg + (size_t)s * (B_ * 4096) + (size_t)b * 4096 + H_;
        hr += ph[j]; hz += ph[H_ + j]; hn += ph[2*H_ + j];
    }
    ir += b_ih[j]        + b_hh[j]        + hr;
    iz += b_ih[H_ + j]   + b_hh[H_ + j]   + hz;
    in_ += b_ih[2*H_ + j];
    hn += b_hh[2*H_ + j];
    float r = 1.f / (1.f + expf(-ir));
    float z = 1.f / (1.f + expf(-iz));
    float n = tanhf(in_ + r * hn);
    float h = (1.f - z) * n + z * h_prev[idx];
    h_out[idx] = h;
    out_seq_t[(size_t)b * (T_ * H_) + j] = h;
}

// ================= attention (block per batch) =============================
__global__ __launch_bounds__(1024)
void attn_kernel(const float* __restrict__ Pq,       // [4][B*4096], q at +0
                 const float* __restrict__ bq,
                 const float* __restrict__ cacheK,   // [B,S,H]
                 const float* __restrict__ v_attn,
                 const int*   __restrict__ mask,
                 const float* __restrict__ context,  // [B,S,C]
                 float* __restrict__ attn_out)       // + t*C, stride T*C
{
    const int b = blockIdx.x;
    const int tid = threadIdx.x;
    const int lane = tid & 63, wave = tid >> 6;

    __shared__ float qb[H_];
    __shared__ float vs[H_];
    __shared__ float sc[S_];
    __shared__ float pr[S_];

    for (int h = tid; h < H_; h += 1024) {
        float q = bq[h];
        #pragma unroll
        for (int s = 0; s < SPLITK; ++s)
            q += Pq[(size_t)s * (B_ * 4096) + (size_t)b * 4096 + h];
        qb[h] = q;
        vs[h] = v_attn[h];
    }
    __syncthreads();

    for (int s = wave; s < S_; s += 16) {
        const float* cr = cacheK + ((size_t)b * S_ + s) * H_;
        float sum = 0.f;
        for (int h = lane; h < H_; h += 64)
            sum += tanhf(qb[h] + cr[h]) * vs[h];
        #pragma unroll
        for (int off = 32; off; off >>= 1) sum += __shfl_down(sum, off, 64);
        if (lane == 0) sc[s] = sum;
    }
    __syncthreads();

    if (wave == 0) {
        float v = (mask[b * S_ + lane] != 0) ? -3.4e38f : sc[lane];
        float mx = v;
        #pragma unroll
        for (int off = 32; off; off >>= 1) mx = fmaxf(mx, __shfl_xor(mx, off, 64));
        float e = expf(v - mx);
        float sum = e;
        #pragma unroll
        for (int off = 32; off; off >>= 1) sum += __shfl_xor(sum, off, 64);
        pr[lane] = e / sum;
    }
    __syncthreads();

    for (int c = tid; c < C_; c += 1024) {
        const float* cb = context + (size_t)b * S_ * C_ + c;
        float sum = 0.f;
        #pragma unroll 8
        for (int s = 0; s < S_; ++s)
            sum += pr[s] * cb[(size_t)s * C_];
        attn_out[(size_t)b * (T_ * C_) + c] = sum;
    }
}

// ================= final logits ============================================
__global__ __launch_bounds__(256)
void final_kernel(const float* __restrict__ L,
                  const float* __restrict__ bi, const float* __restrict__ bh,
                  const float* __restrict__ bc,
                  const float* __restrict__ h_cur,
                  float* __restrict__ out)
{
    int i = blockIdx.x * 256 + threadIdx.x;
    const int total = B_ * T_ * E_;
    if (i < total) {
        int e = i & (E_ - 1);
        out[i] = tanhf(L[i] + bi[e] + bh[e] + bc[e]);
    } else if (i < total + B_ * H_) {
        out[i] = h_cur[i - total];
    }
}

extern "C" void kernel_launch(void* const* d_in, const int* in_sizes, int n_in,
                              void* d_out, int out_size, void* d_ws, size_t ws_size,
                              hipStream_t stream)
{
    const int*   y       = (const int*)  d_in[0];
    const float* context = (const float*)d_in[1];
    const int*   cmask   = (const int*)  d_in[2];
    const float* hidden  = (const float*)d_in[3];
    const float* emb     = (const float*)d_in[4];
    const float* W_ih1   = (const float*)d_in[5];
    const float* W_hh1   = (const float*)d_in[6];
    const float* b_ih1   = (const float*)d_in[7];
    const float* b_hh1   = (const float*)d_in[8];
    const float* Wq      = (const float*)d_in[9];
    const float* bq      = (const float*)d_in[10];
    const float* Wk      = (const float*)d_in[11];
    const float* v_attn  = (const float*)d_in[12];
    const float* W_ih2   = (const float*)d_in[13];
    const float* W_hh2   = (const float*)d_in[14];
    const float* b_ih2   = (const float*)d_in[15];
    const float* b_hh2   = (const float*)d_in[16];
    const float* Wi      = (const float*)d_in[17];
    const float* bi      = (const float*)d_in[18];
    const float* Wh      = (const float*)d_in[19];
    const float* bh      = (const float*)d_in[20];
    const float* Wc      = (const float*)d_in[21];
    const float* bc      = (const float*)d_in[22];

    float* ws = (float*)d_ws;
    size_t off = 0;
    float* x        = ws + off; off += (size_t)B_ * T_ * E_;
    float* Xg       = ws + off; off += (size_t)B_ * T_ * G_;
    float* Xi       = ws + off; off += (size_t)B_ * T_ * E_;
    float* cacheK   = ws + off; off += (size_t)B_ * S_ * H_;
    float* attn_seq = ws + off; off += (size_t)B_ * T_ * C_;
    float* out_seq  = ws + off; off += (size_t)B_ * T_ * H_;
    float* Wcat     = ws + off; off += (size_t)4096 * H_;      // [WqT ; W_hh2]
    float* P_A      = ws + off; off += (size_t)SPLITK * B_ * G_;
    float* P_B      = ws + off; off += (size_t)SPLITK * B_ * 4096;
    float* h1       = ws + off; off += (size_t)B_ * H_;
    float* h_cur    = ws + off; off += (size_t)B_ * H_;

    // ---- one-time prep ----
    embed_kernel<<<(B_*T_*E_/4 + 255)/256, 256, 0, stream>>>(y, emb, x);
    transpose_kernel<<<dim3(H_/32, H_/32), dim3(32,32), 0, stream>>>(Wq, Wcat, H_, H_);
    copy4_kernel<<<(G_*H_/4)/256, 256, 0, stream>>>(W_hh2, Wcat + (size_t)H_*H_);

    // Xg = x @ W_ih1^T  [2048,3072] K=512
    gemm128<true, false><<<dim3(G_/128, (B_*T_)/128), 256, 0, stream>>>(
        x, E_, W_ih1, Xg, B_*T_, G_, E_);
    // Xi = x @ Wi^T  [2048,512] K=512
    gemm128<true, false><<<dim3(E_/128, (B_*T_)/128), 256, 0, stream>>>(
        x, E_, Wi, Xi, B_*T_, E_, E_);
    // cacheK = context @ Wk  [4096,1024] K=2048
    gemm128<false, false><<<dim3(H_/128, (B_*S_)/128), 256, 0, stream>>>(
        context, C_, Wk, cacheK, B_*S_, H_, C_);

    // ---- sequential scan ----
    for (int t = 0; t < T_; ++t) {
        const float* hprev = (t == 0) ? hidden : h_cur;

        // gh1 partials = hprev @ W_hh1^T  N=3072 K=1024
        splitk_gemm<<<dim3(G_/64, SPLITK), 256, 0, stream>>>(
            hprev, H_, W_hh1, P_A, G_, H_);

        gru1_kernel<<<(B_*H_)/256, 256, 0, stream>>>(
            Xg + (size_t)t * G_, P_A, b_ih1, b_hh1, hprev, h1);

        // [q ; gh2] partials = h1 @ Wcat^T  N=4096 K=1024
        splitk_gemm<<<dim3(4096/64, SPLITK), 256, 0, stream>>>(
            h1, H_, Wcat, P_B, 4096, H_);

        attn_kernel<<<B_, 1024, 0, stream>>>(
            P_B, bq, cacheK, v_attn, cmask, context, attn_seq + (size_t)t * C_);

        // gi2 partials = attn_t @ W_ih2^T  N=3072 K=2048
        splitk_gemm<<<dim3(G_/64, SPLITK), 256, 0, stream>>>(
            attn_seq + (size_t)t * C_, T_ * C_, W_ih2, P_A, G_, C_);

        gru2_kernel<<<(B_*H_)/256, 256, 0, stream>>>(
            P_A, P_B, b_ih2, b_hh2, h1, h_cur, out_seq + (size_t)t * H_);
    }

    // ---- epilogue ----
    gemm128<true, true><<<dim3(E_/128, (B_*T_)/128), 256, 0, stream>>>(
        out_seq, H_, Wh, Xi, B_*T_, E_, H_);
    gemm128<true, true><<<dim3(E_/128, (B_*T_)/128), 256, 0, stream>>>(
        attn_seq, C_, Wc, Xi, B_*T_, E_, C_);

    const int total_out = B_*T_*E_ + B_*H_;
    final_kernel<<<(total_out + 255)/256, 256, 0, stream>>>(
        Xi, bi, bh, bc, h_cur, (float*)d_out);
}